// Round 1
// baseline (769.171 us; speedup 1.0000x reference)
//
#include <hip/hip_runtime.h>
#include <stdint.h>

typedef __attribute__((ext_vector_type(8))) short short8;
typedef __attribute__((ext_vector_type(4))) float floatx4;

__device__ __forceinline__ unsigned short f2b_rne(float f) {
  union { float f; unsigned u; } c; c.f = f;
  unsigned u = c.u;
  unsigned r = u + 0x7fffu + ((u >> 16) & 1u);
  return (unsigned short)(r >> 16);
}

__device__ __forceinline__ short8 cvt8(float4 a, float4 b) {
  union { short8 s; unsigned u[4]; } r;
  r.u[0] = ((unsigned)f2b_rne(a.y) << 16) | f2b_rne(a.x);
  r.u[1] = ((unsigned)f2b_rne(a.w) << 16) | f2b_rne(a.z);
  r.u[2] = ((unsigned)f2b_rne(b.y) << 16) | f2b_rne(b.x);
  r.u[3] = ((unsigned)f2b_rne(b.w) << 16) | f2b_rne(b.z);
  return r.s;
}

// ---------------------------------------------------------------------------
// Weight prep: Wt[n][k] = bf16(W_seg[k][c])  (B^T layout, K contiguous)
// rows 0..255=W_val, 256..511=W_so, 512..767=W_tso.
// rows 768..1023: head-interleaved aw layout — for idx=n-768, h=idx>>5,
// w=idx&31: w<16 -> W_aw col h*16+w ; w>=16 -> W_taw col h*16+(w-16).
// This puts each head's 32 joint-softmax logits in one contiguous 32-col
// group so the softmax reduces within a 16-lane shfl group (no LDS).
// bcat[n] = matching bias.
// ---------------------------------------------------------------------------
__global__ void prep_weights(const float* __restrict__ Wv,  const float* __restrict__ bv,
                             const float* __restrict__ Wso, const float* __restrict__ bso,
                             const float* __restrict__ Waw, const float* __restrict__ baw,
                             const float* __restrict__ Wtso,const float* __restrict__ btso,
                             const float* __restrict__ Wtaw,const float* __restrict__ btaw,
                             unsigned short* __restrict__ Wt, float* __restrict__ bcat) {
  int n = blockIdx.x;   // 0..1023
  int k = threadIdx.x;  // 0..255
  const float* W; const float* b; int c, N;
  if (n < 256)      { W = Wv;   b = bv;   c = n;       N = 256; }
  else if (n < 512) { W = Wso;  b = bso;  c = n - 256; N = 256; }
  else if (n < 768) { W = Wtso; b = btso; c = n - 512; N = 256; }
  else {
    int idx = n - 768, h = idx >> 5, w = idx & 31;
    if (w < 16) { W = Waw;  b = baw;  c = h * 16 + w;        N = 128; }
    else        { W = Wtaw; b = btaw; c = h * 16 + (w - 16); N = 128; }
  }
  Wt[n * 256 + k] = f2b_rne(W[(size_t)k * N + c]);
  if (k == 0) bcat[n] = b[c];
}

// ---------------------------------------------------------------------------
// Fused GEMM, no LDS, no barriers. Grid (8, M/128):
//   nt 0..1: value = X @ Wv      -> out seg 0
//   nt 2..3: curr_off = Q @ Wso  -> out seg 1
//   nt 4..5: temp_off = Q @ Wtso -> out seg 2
//   nt 6..7: aw logits = Q @ [Waw|Wtaw] (head-interleaved) -> fused softmax
// Each wave computes a 64x64 tile as 4x4 MFMA 16x16x32, loading A (fp32,
// converted in-register to bf16) and B (bf16, L2-resident 512 KB) fragments
// directly from global. All k-loop addresses are immediate offsets off 8
// hoisted base pointers: zero address math, zero sync in the hot loop.
// ---------------------------------------------------------------------------
__global__ __launch_bounds__(256, 3)
void gemm_fused(const float* __restrict__ Q, const float* __restrict__ X,
                const unsigned short* __restrict__ Wt, const float* __restrict__ bcat,
                float* __restrict__ out, int M) {
  const int nt = blockIdx.x;     // 0..7
  const int mt = blockIdx.y;
  const int mBase = mt * 128;
  const int nBase = nt * 128;
  const float* A = (nt < 2) ? X : Q;

  const int tid  = threadIdx.x;
  const int lane = tid & 63;
  const int wid  = tid >> 6;
  const int mw   = (wid >> 1) * 64;
  const int nw   = (wid & 1) * 64;
  const int lrow = lane & 15;
  const int quad = lane >> 4;

  const float* a0 = A + (size_t)(mBase + mw + lrow) * 256 + quad * 8;
  const unsigned short* b0 = Wt + (size_t)(nBase + nw + lrow) * 256 + quad * 8;
  const float* ap[4];
  const unsigned short* bp[4];
#pragma unroll
  for (int i = 0; i < 4; ++i) {
    ap[i] = a0 + i * 16 * 256;
    bp[i] = b0 + i * 16 * 256;
  }

  floatx4 acc[4][4] = {};

#pragma unroll
  for (int s = 0; s < 8; ++s) {
    short8 af[4], bf[4];
#pragma unroll
    for (int mi = 0; mi < 4; ++mi) {
      float4 x0 = *(const float4*)(ap[mi] + s * 32);
      float4 x1 = *(const float4*)(ap[mi] + s * 32 + 4);
      af[mi] = cvt8(x0, x1);
    }
#pragma unroll
    for (int ni = 0; ni < 4; ++ni)
      bf[ni] = *(const short8*)(bp[ni] + s * 32);
#pragma unroll
    for (int mi = 0; mi < 4; ++mi)
#pragma unroll
      for (int ni = 0; ni < 4; ++ni)
        acc[mi][ni] = __builtin_amdgcn_mfma_f32_16x16x32_bf16(af[mi], bf[ni], acc[mi][ni], 0, 0, 0);
  }

  // C/D layout: col = lane&15, row = quad*4 + reg (16x16x32 bf16, m89-verified)
  if (nt < 6) {
    // ---- plain epilogue: bias + store ----
    const int seg  = nt >> 1;
    const int half = nt & 1;
    float* Oseg = out + (size_t)seg * ((size_t)M * 256) + (size_t)half * 128;
#pragma unroll
    for (int ni = 0; ni < 4; ++ni) {
      float bias = bcat[nBase + nw + ni * 16 + lrow];
#pragma unroll
      for (int mi = 0; mi < 4; ++mi) {
#pragma unroll
        for (int r = 0; r < 4; ++r) {
          int row = mBase + mw + mi * 16 + quad * 4 + r;
          int col = nw + ni * 16 + lrow;
          Oseg[(size_t)row * 256 + col] = acc[mi][ni][r] + bias;
        }
      }
    }
  } else {
    // ---- aw epilogue: joint softmax over 32 logits per (row, head) ----
    // wave's 64 cols = 2 complete head groups (hg): cols nw+hg*32 .. +31.
    // For a fixed output row, the 32 logits of one head live in the 16 lanes
    // of this quad-group (lrow) x 2 fragments (ni = 2*hg caw, 2*hg+1 taw).
    float* awc = out + (size_t)3 * ((size_t)M * 256);
    float* awt = awc + (size_t)M * 128;
    float bias[4];
#pragma unroll
    for (int ni = 0; ni < 4; ++ni) bias[ni] = bcat[nBase + nw + ni * 16 + lrow];
    const int hbase = ((nt - 6) * 128 + nw) >> 5;   // head index of hg=0
#pragma unroll
    for (int mi = 0; mi < 4; ++mi) {
#pragma unroll
      for (int r = 0; r < 4; ++r) {
        const int row = mBase + mw + mi * 16 + quad * 4 + r;
#pragma unroll
        for (int hg = 0; hg < 2; ++hg) {
          float a = acc[mi][2 * hg + 0][r] + bias[2 * hg + 0];   // caw logit
          float b = acc[mi][2 * hg + 1][r] + bias[2 * hg + 1];   // taw logit
          float mx = fmaxf(a, b);
          mx = fmaxf(mx, __shfl_xor(mx, 1));
          mx = fmaxf(mx, __shfl_xor(mx, 2));
          mx = fmaxf(mx, __shfl_xor(mx, 4));
          mx = fmaxf(mx, __shfl_xor(mx, 8));
          float ea = __expf(a - mx), eb = __expf(b - mx);
          float ssum = ea + eb;
          ssum += __shfl_xor(ssum, 1);
          ssum += __shfl_xor(ssum, 2);
          ssum += __shfl_xor(ssum, 4);
          ssum += __shfl_xor(ssum, 8);
          float inv = 1.0f / ssum;
          const int h = hbase + hg;
          awc[(size_t)row * 128 + h * 16 + lrow] = ea * inv;
          awt[(size_t)row * 128 + h * 16 + lrow] = eb * inv;
        }
      }
    }
  }
}

// ---------------------------------------------------------------------------
extern "C" void kernel_launch(void* const* d_in, const int* in_sizes, int n_in,
                              void* d_out, int out_size, void* d_ws, size_t ws_size,
                              hipStream_t stream) {
  const float* Q    = (const float*)d_in[0];
  const float* Xf   = (const float*)d_in[1];
  const float* Wv   = (const float*)d_in[2];
  const float* bv   = (const float*)d_in[3];
  const float* Wso  = (const float*)d_in[4];
  const float* bso  = (const float*)d_in[5];
  const float* Waw  = (const float*)d_in[6];
  const float* baw  = (const float*)d_in[7];
  const float* Wtso = (const float*)d_in[8];
  const float* btso = (const float*)d_in[9];
  const float* Wtaw = (const float*)d_in[10];
  const float* btaw = (const float*)d_in[11];
  float* out = (float*)d_out;

  unsigned short* Wt = (unsigned short*)d_ws;               // 512 KB
  float* bcat = (float*)((char*)d_ws + 1024 * 256 * 2);     // 4 KB

  int M = in_sizes[0] / 256;  // 97920

  prep_weights<<<1024, 256, 0, stream>>>(Wv, bv, Wso, bso, Waw, baw,
                                         Wtso, btso, Wtaw, btaw, Wt, bcat);

  dim3 g(8, M / 128);  // nt fastest: all 8 n-tiles of one m-panel co-temporal
  gemm_fused<<<g, 256, 0, stream>>>(Q, Xf, Wt, bcat, out, M);
}

// Round 2
// 697.073 us; speedup vs baseline: 1.1034x; 1.1034x over previous
//
#include <hip/hip_runtime.h>
#include <stdint.h>

typedef __attribute__((ext_vector_type(8))) short short8;
typedef __attribute__((ext_vector_type(4))) float floatx4;

__device__ __forceinline__ unsigned short f2b_rne(float f) {
  union { float f; unsigned u; } c; c.f = f;
  unsigned u = c.u;
  unsigned r = u + 0x7fffu + ((u >> 16) & 1u);
  return (unsigned short)(r >> 16);
}

__device__ __forceinline__ short8 cvt8(float4 a, float4 b) {
  union { short8 s; unsigned u[4]; } r;
  r.u[0] = ((unsigned)f2b_rne(a.y) << 16) | f2b_rne(a.x);
  r.u[1] = ((unsigned)f2b_rne(a.w) << 16) | f2b_rne(a.z);
  r.u[2] = ((unsigned)f2b_rne(b.y) << 16) | f2b_rne(b.x);
  r.u[3] = ((unsigned)f2b_rne(b.w) << 16) | f2b_rne(b.z);
  return r.s;
}

// ---------------------------------------------------------------------------
// Weight prep: Wt[n][k] = bf16(W_seg[k][c])  (B^T layout, K contiguous)
// rows 0..255=W_val, 256..511=W_so, 512..767=W_tso.
// rows 768..1023: head-interleaved aw layout — for idx=n-768, h=idx>>5,
// w=idx&31: w<16 -> W_aw col h*16+w ; w>=16 -> W_taw col h*16+(w-16).
// Each head's 32 joint-softmax logits occupy one contiguous 32-col group so
// the softmax reduces inside a 16-lane shfl group (no LDS, no extra kernel).
// ---------------------------------------------------------------------------
__global__ void prep_weights(const float* __restrict__ Wv,  const float* __restrict__ bv,
                             const float* __restrict__ Wso, const float* __restrict__ bso,
                             const float* __restrict__ Waw, const float* __restrict__ baw,
                             const float* __restrict__ Wtso,const float* __restrict__ btso,
                             const float* __restrict__ Wtaw,const float* __restrict__ btaw,
                             unsigned short* __restrict__ Wt, float* __restrict__ bcat) {
  int n = blockIdx.x;   // 0..1023
  int k = threadIdx.x;  // 0..255
  const float* W; const float* b; int c, N;
  if (n < 256)      { W = Wv;   b = bv;   c = n;       N = 256; }
  else if (n < 512) { W = Wso;  b = bso;  c = n - 256; N = 256; }
  else if (n < 768) { W = Wtso; b = btso; c = n - 512; N = 256; }
  else {
    int idx = n - 768, h = idx >> 5, w = idx & 31;
    if (w < 16) { W = Waw;  b = baw;  c = h * 16 + w;        N = 128; }
    else        { W = Wtaw; b = btaw; c = h * 16 + (w - 16); N = 128; }
  }
  Wt[n * 256 + k] = f2b_rne(W[(size_t)k * N + c]);
  if (k == 0) bcat[n] = b[c];
}

// ---------------------------------------------------------------------------
// One block per 128-row m-panel computes ALL 1024 output columns.
//   Phase 1: stage X panel (fp32->bf16, XOR-swizzled LDS) -> value (cols 0..255)
//   Phase 2: restage Q panel into same LDS -> so (256..511), tso (512..767),
//            aw logits (768..1023) + fused per-head softmax.
// A read from HBM exactly once. B fragments read directly from the 512 KB
// L2-resident Wt (every block reads it -> L2 hit). K-loops have NO barriers;
// only 4 __syncthreads per block total. 8 waves = 2(m) x 4(n), each 64x64.
// ---------------------------------------------------------------------------
__global__ __launch_bounds__(512, 4)
void gemm_panel(const float* __restrict__ Q, const float* __restrict__ X,
                const unsigned short* __restrict__ Wt, const float* __restrict__ bcat,
                float* __restrict__ out, int M) {
  __shared__ __align__(16) unsigned short As[128 * 256];  // 64 KB

  const int mt = blockIdx.x;
  const int mBase = mt * 128;
  const int tid  = threadIdx.x;
  const int lane = tid & 63;
  const int wid  = tid >> 6;
  const int wm   = (wid >> 2) * 64;   // wave m-offset: 0 or 64
  const int wn   = wid & 3;           // wave n-slot: 0..3 (64 cols each)
  const int lrow = lane & 15;
  const int quad = lane >> 4;
  const int swz  = lrow & 7;

  // ---- stage: 128x256 fp32 -> bf16 into XOR-swizzled LDS (8 chunks/thread)
  auto stage = [&](const float* __restrict__ src) {
#pragma unroll
    for (int i = 0; i < 8; ++i) {
      int c = i * 512 + tid;          // chunk id 0..4095 (8 bf16 each)
      int row = c >> 5, ck = c & 31;
      const float* g = src + (size_t)(mBase + row) * 256 + ck * 8;
      float4 x0 = *(const float4*)g;
      float4 x1 = *(const float4*)(g + 4);
      *(short8*)&As[row * 256 + ((ck ^ (row & 7)) << 3)] = cvt8(x0, x1);
    }
  };

  // ---- K-loop for one 64x64 wave tile; nbase = global weight-row base
  auto compute = [&](int nbase, floatx4 (&acc)[4][4]) {
    const unsigned short* b0 = Wt + (size_t)(nbase + lrow) * 256 + quad * 8;
#pragma unroll
    for (int s = 0; s < 8; ++s) {
      short8 af[4], bf[4];
#pragma unroll
      for (int mi = 0; mi < 4; ++mi) {
        int row = wm + mi * 16 + lrow;
        int chunk = s * 4 + quad;
        af[mi] = *(const short8*)&As[row * 256 + ((chunk ^ swz) << 3)];
      }
#pragma unroll
      for (int ni = 0; ni < 4; ++ni)
        bf[ni] = *(const short8*)(b0 + (size_t)(ni * 16) * 256 + s * 32);
#pragma unroll
      for (int mi = 0; mi < 4; ++mi)
#pragma unroll
        for (int ni = 0; ni < 4; ++ni)
          acc[mi][ni] = __builtin_amdgcn_mfma_f32_16x16x32_bf16(af[mi], bf[ni], acc[mi][ni], 0, 0, 0);
    }
  };

  // ---- plain epilogue: bias + store (C/D: col=lane&15, row=quad*4+reg)
  auto store_plain = [&](floatx4 (&acc)[4][4], float* __restrict__ Oseg, int nbase) {
    int colb = (nbase & 255);
#pragma unroll
    for (int ni = 0; ni < 4; ++ni) {
      float bias = bcat[nbase + ni * 16 + lrow];
#pragma unroll
      for (int mi = 0; mi < 4; ++mi) {
#pragma unroll
        for (int r = 0; r < 4; ++r) {
          int row = mBase + wm + mi * 16 + quad * 4 + r;
          Oseg[(size_t)row * 256 + colb + ni * 16 + lrow] = acc[mi][ni][r] + bias;
        }
      }
    }
  };

  // ================= Phase 1: value = X @ Wv =================
  stage(X);
  __syncthreads();
  {
    floatx4 acc[4][4] = {};
    compute(wn * 64, acc);
    store_plain(acc, out, wn * 64);
  }
  __syncthreads();              // all waves done reading X from LDS

  // ================= Phase 2: Q-based outputs =================
  stage(Q);
  __syncthreads();

#pragma unroll 1
  for (int it = 1; it < 4; ++it) {
    floatx4 acc[4][4] = {};
    const int nbase = it * 256 + wn * 64;
    compute(nbase, acc);
    if (it < 3) {
      store_plain(acc, out + (size_t)it * ((size_t)M * 256), nbase);
    } else {
      // ---- aw: joint softmax over 32 logits per (row, head) ----
      float* awc = out + (size_t)3 * ((size_t)M * 256);
      float* awt = awc + (size_t)M * 128;
      float bias[4];
#pragma unroll
      for (int ni = 0; ni < 4; ++ni) bias[ni] = bcat[nbase + ni * 16 + lrow];
      const int hbase = wn * 2;   // 2 heads per wave (32 cols each)
#pragma unroll
      for (int mi = 0; mi < 4; ++mi) {
#pragma unroll
        for (int r = 0; r < 4; ++r) {
          const int row = mBase + wm + mi * 16 + quad * 4 + r;
#pragma unroll
          for (int hg = 0; hg < 2; ++hg) {
            float a = acc[mi][2 * hg + 0][r] + bias[2 * hg + 0];   // caw logit
            float b = acc[mi][2 * hg + 1][r] + bias[2 * hg + 1];   // taw logit
            float mx = fmaxf(a, b);
            mx = fmaxf(mx, __shfl_xor(mx, 1));
            mx = fmaxf(mx, __shfl_xor(mx, 2));
            mx = fmaxf(mx, __shfl_xor(mx, 4));
            mx = fmaxf(mx, __shfl_xor(mx, 8));
            float ea = __expf(a - mx), eb = __expf(b - mx);
            float ssum = ea + eb;
            ssum += __shfl_xor(ssum, 1);
            ssum += __shfl_xor(ssum, 2);
            ssum += __shfl_xor(ssum, 4);
            ssum += __shfl_xor(ssum, 8);
            float inv = 1.0f / ssum;
            const int h = hbase + hg;
            awc[(size_t)row * 128 + h * 16 + lrow] = ea * inv;
            awt[(size_t)row * 128 + h * 16 + lrow] = eb * inv;
          }
        }
      }
    }
  }
}

// ---------------------------------------------------------------------------
extern "C" void kernel_launch(void* const* d_in, const int* in_sizes, int n_in,
                              void* d_out, int out_size, void* d_ws, size_t ws_size,
                              hipStream_t stream) {
  const float* Q    = (const float*)d_in[0];
  const float* Xf   = (const float*)d_in[1];
  const float* Wv   = (const float*)d_in[2];
  const float* bv   = (const float*)d_in[3];
  const float* Wso  = (const float*)d_in[4];
  const float* bso  = (const float*)d_in[5];
  const float* Waw  = (const float*)d_in[6];
  const float* baw  = (const float*)d_in[7];
  const float* Wtso = (const float*)d_in[8];
  const float* btso = (const float*)d_in[9];
  const float* Wtaw = (const float*)d_in[10];
  const float* btaw = (const float*)d_in[11];
  float* out = (float*)d_out;

  unsigned short* Wt = (unsigned short*)d_ws;               // 512 KB
  float* bcat = (float*)((char*)d_ws + 1024 * 256 * 2);     // 4 KB

  int M = in_sizes[0] / 256;  // 97920

  prep_weights<<<1024, 256, 0, stream>>>(Wv, bv, Wso, bso, Waw, baw,
                                         Wtso, btso, Wtaw, btaw, Wt, bcat);

  gemm_panel<<<M / 128, 512, 0, stream>>>(Q, Xf, Wt, bcat, out, M);
}

// Round 3
// 625.274 us; speedup vs baseline: 1.2301x; 1.1148x over previous
//
#include <hip/hip_runtime.h>
#include <stdint.h>

#define AS1 __attribute__((address_space(1)))
#define AS3 __attribute__((address_space(3)))

typedef __attribute__((ext_vector_type(8))) short short8;
typedef __attribute__((ext_vector_type(4))) float floatx4;

__device__ __forceinline__ unsigned short f2b_rne(float f) {
  union { float f; unsigned u; } c; c.f = f;
  unsigned u = c.u;
  unsigned r = u + 0x7fffu + ((u >> 16) & 1u);
  return (unsigned short)(r >> 16);
}

__device__ __forceinline__ uint2 pack8(float4 a, float4 b) {
  uint2 pk;
  pk.x = ((unsigned)f2b_rne(a.y) << 16) | f2b_rne(a.x);
  pk.y = ((unsigned)f2b_rne(a.w) << 16) | f2b_rne(a.z);
  // second half packed by caller with a second pack8 call on (b, ...)
  (void)b;
  return pk;
}

// ---------------------------------------------------------------------------
// Weight prep: Wt[n][k] = bf16(W_seg[k][c])  (B^T layout, K contiguous)
// rows 0..255=W_val, 256..511=W_so, 512..767=W_tso.
// rows 768..1023: head-interleaved aw layout — idx=n-768, h=idx>>5, w=idx&31:
// w<16 -> W_aw col h*16+w ; w>=16 -> W_taw col h*16+(w-16). Each head's 32
// joint-softmax logits are one contiguous 32-col group -> shfl softmax.
// ---------------------------------------------------------------------------
__global__ void prep_weights(const float* __restrict__ Wv,  const float* __restrict__ bv,
                             const float* __restrict__ Wso, const float* __restrict__ bso,
                             const float* __restrict__ Waw, const float* __restrict__ baw,
                             const float* __restrict__ Wtso,const float* __restrict__ btso,
                             const float* __restrict__ Wtaw,const float* __restrict__ btaw,
                             unsigned short* __restrict__ Wt, float* __restrict__ bcat) {
  int n = blockIdx.x;   // 0..1023
  int k = threadIdx.x;  // 0..255
  const float* W; const float* b; int c, N;
  if (n < 256)      { W = Wv;   b = bv;   c = n;       N = 256; }
  else if (n < 512) { W = Wso;  b = bso;  c = n - 256; N = 256; }
  else if (n < 768) { W = Wtso; b = btso; c = n - 512; N = 256; }
  else {
    int idx = n - 768, h = idx >> 5, w = idx & 31;
    if (w < 16) { W = Waw;  b = baw;  c = h * 16 + w;        N = 128; }
    else        { W = Wtaw; b = btaw; c = h * 16 + (w - 16); N = 128; }
  }
  Wt[n * 256 + k] = f2b_rne(W[(size_t)k * N + c]);
  if (k == 0) bcat[n] = b[c];
}

// ---------------------------------------------------------------------------
// Main GEMM, grid (8, M/128), 128x128 tile, BK=64 (4 k-steps, 8 barriers).
//   nt 0..1: value = X @ Wv   nt 2..3: so   nt 4..5: tso
//   nt 6..7: aw logits (head-interleaved) + fused 16-lane shfl softmax.
// B staged via global_load_lds (linear LDS dest, PRE-SWIZZLED global source);
// A staged fp32->bf16 via swizzled ds_write_b64. Fragment reads use the same
// 16B-granule XOR swizzle (kc ^ (row&7)) -> 2-way banks = free.
// ---------------------------------------------------------------------------
__global__ __launch_bounds__(256, 3)
void gemm_main(const float* __restrict__ Q, const float* __restrict__ X,
               const unsigned short* __restrict__ Wt, const float* __restrict__ bcat,
               float* __restrict__ out, int M) {
  __shared__ __align__(16) unsigned short As[128 * 64];  // 16 KB
  __shared__ __align__(16) unsigned short Bs[128 * 64];  // 16 KB

  const int nt = blockIdx.x;     // 0..7
  const int mt = blockIdx.y;
  const int mBase = mt * 128;
  const int nBase = nt * 128;
  const float* A = (nt < 2) ? X : Q;

  const int tid  = threadIdx.x;
  const int lane = tid & 63;
  const int wid  = tid >> 6;
  const int mw   = (wid >> 1) * 64;
  const int nw   = (wid & 1) * 64;
  const int lrow = lane & 15;
  const int quad = lane >> 4;

  floatx4 acc[4][4] = {};

  const float* Ab = A + (size_t)mBase * 256;
  const unsigned short* Bb = Wt + (size_t)nBase * 256;

  for (int s = 0; s < 4; ++s) {
    const int k0 = s * 64;
    __syncthreads();
    // ---- B stage: 128x64 bf16 = 1024 x 16B chunks, 4/thread.
    // LDS dest linear (chunk*16); global source column pre-swizzled so that
    // LDS (r, kc) holds global column-chunk (kc ^ (r&7)).
#pragma unroll
    for (int j = 0; j < 4; ++j) {
      int ch = j * 256 + tid;
      int r = ch >> 3, kc = ch & 7;
      const unsigned short* g = Bb + (size_t)r * 256 + k0 + ((kc ^ (r & 7)) << 3);
      unsigned ldsoff = (unsigned)((j * 256 + (tid & ~63)) * 16);  // wave-uniform
      __builtin_amdgcn_global_load_lds((const AS1 void*)g,
                                       (AS3 void*)(((char*)Bs) + ldsoff), 16, 0, 0);
    }
    // ---- A stage: 128x64 fp32 -> bf16: 2048 float4 chunks, 8/thread ----
    float4 va[8];
#pragma unroll
    for (int i = 0; i < 8; ++i) {
      int id = i * 256 + tid;
      int r = id >> 4, kc4 = id & 15;
      va[i] = *(const float4*)(Ab + (size_t)r * 256 + k0 + kc4 * 4);
    }
#pragma unroll
    for (int i = 0; i < 8; ++i) {
      int id = i * 256 + tid;
      int r = id >> 4, kc4 = id & 15;
      uint2 pk;
      pk.x = ((unsigned)f2b_rne(va[i].y) << 16) | f2b_rne(va[i].x);
      pk.y = ((unsigned)f2b_rne(va[i].w) << 16) | f2b_rne(va[i].z);
      int idx = r * 64 + ((((kc4 >> 1) ^ (r & 7)) << 3) + (kc4 & 1) * 4);
      *(uint2*)&As[idx] = pk;
    }
    __syncthreads();
    // ---- compute: wave does 64x64 = 4x4 of 16x16x32, two k-halves ----
    short8 af[2][4], bf[2][4];
#pragma unroll
    for (int t = 0; t < 2; ++t) {
#pragma unroll
      for (int mi = 0; mi < 4; ++mi) {
        int row = mw + mi * 16 + lrow;
        af[t][mi] = *(const short8*)&As[row * 64 + (((t * 4 + quad) ^ (row & 7)) << 3)];
      }
#pragma unroll
      for (int ni = 0; ni < 4; ++ni) {
        int row = nw + ni * 16 + lrow;
        bf[t][ni] = *(const short8*)&Bs[row * 64 + (((t * 4 + quad) ^ (row & 7)) << 3)];
      }
    }
#pragma unroll
    for (int t = 0; t < 2; ++t)
#pragma unroll
      for (int mi = 0; mi < 4; ++mi)
#pragma unroll
        for (int ni = 0; ni < 4; ++ni)
          acc[mi][ni] = __builtin_amdgcn_mfma_f32_16x16x32_bf16(af[t][mi], bf[t][ni], acc[mi][ni], 0, 0, 0);
  }

  // C/D layout: col = lane&15, row = quad*4 + reg (16x16x32 bf16, m89-verified)
  if (nt < 6) {
    const int seg  = nt >> 1;
    const int half = nt & 1;
    float* Oseg = out + (size_t)seg * ((size_t)M * 256) + (size_t)half * 128;
#pragma unroll
    for (int ni = 0; ni < 4; ++ni) {
      float bias = bcat[nBase + nw + ni * 16 + lrow];
#pragma unroll
      for (int mi = 0; mi < 4; ++mi) {
#pragma unroll
        for (int r = 0; r < 4; ++r) {
          int row = mBase + mw + mi * 16 + quad * 4 + r;
          int col = nw + ni * 16 + lrow;
          Oseg[(size_t)row * 256 + col] = acc[mi][ni][r] + bias;
        }
      }
    }
  } else {
    // ---- aw: joint softmax over 32 logits per (row, head); wave = 2 heads.
    float* awc = out + (size_t)3 * ((size_t)M * 256);
    float* awt = awc + (size_t)M * 128;
    float bias[4];
#pragma unroll
    for (int ni = 0; ni < 4; ++ni) bias[ni] = bcat[nBase + nw + ni * 16 + lrow];
    const int hbase = ((nt - 6) * 128 + nw) >> 5;
#pragma unroll
    for (int mi = 0; mi < 4; ++mi) {
#pragma unroll
      for (int r = 0; r < 4; ++r) {
        const int row = mBase + mw + mi * 16 + quad * 4 + r;
#pragma unroll
        for (int hg = 0; hg < 2; ++hg) {
          float a = acc[mi][2 * hg + 0][r] + bias[2 * hg + 0];   // caw logit
          float b = acc[mi][2 * hg + 1][r] + bias[2 * hg + 1];   // taw logit
          float mx = fmaxf(a, b);
          mx = fmaxf(mx, __shfl_xor(mx, 1));
          mx = fmaxf(mx, __shfl_xor(mx, 2));
          mx = fmaxf(mx, __shfl_xor(mx, 4));
          mx = fmaxf(mx, __shfl_xor(mx, 8));
          float ea = __expf(a - mx), eb = __expf(b - mx);
          float ssum = ea + eb;
          ssum += __shfl_xor(ssum, 1);
          ssum += __shfl_xor(ssum, 2);
          ssum += __shfl_xor(ssum, 4);
          ssum += __shfl_xor(ssum, 8);
          float inv = 1.0f / ssum;
          const int h = hbase + hg;
          awc[(size_t)row * 128 + h * 16 + lrow] = ea * inv;
          awt[(size_t)row * 128 + h * 16 + lrow] = eb * inv;
        }
      }
    }
  }
}

// ---------------------------------------------------------------------------
extern "C" void kernel_launch(void* const* d_in, const int* in_sizes, int n_in,
                              void* d_out, int out_size, void* d_ws, size_t ws_size,
                              hipStream_t stream) {
  const float* Q    = (const float*)d_in[0];
  const float* Xf   = (const float*)d_in[1];
  const float* Wv   = (const float*)d_in[2];
  const float* bv   = (const float*)d_in[3];
  const float* Wso  = (const float*)d_in[4];
  const float* bso  = (const float*)d_in[5];
  const float* Waw  = (const float*)d_in[6];
  const float* baw  = (const float*)d_in[7];
  const float* Wtso = (const float*)d_in[8];
  const float* btso = (const float*)d_in[9];
  const float* Wtaw = (const float*)d_in[10];
  const float* btaw = (const float*)d_in[11];
  float* out = (float*)d_out;

  unsigned short* Wt = (unsigned short*)d_ws;               // 512 KB
  float* bcat = (float*)((char*)d_ws + 1024 * 256 * 2);     // 4 KB

  int M = in_sizes[0] / 256;  // 97920

  prep_weights<<<1024, 256, 0, stream>>>(Wv, bv, Wso, bso, Waw, baw,
                                         Wtso, btso, Wtaw, btaw, Wt, bcat);

  dim3 g(8, M / 128);  // nt fastest: all 8 n-tiles of an m-panel co-temporal
  gemm_main<<<g, 256, 0, stream>>>(Q, Xf, Wt, bcat, out, M);
}